// Round 1
// baseline (342.838 us; speedup 1.0000x reference)
//
#include <hip/hip_runtime.h>
#include <math.h>

#define D_ 8
#define H_ 64
#define IN_ 17
#define SLOPE_ 0.2f
#define B_ 128
#define T_ 514
#define W_ 512
#define N_ (B_*W_)            // 65536
#define RES_SZ (N_*D_)        // 524288
#define LOG_OFF RES_SZ        // 524288
#define HJ_OFF (RES_SZ + B_)  // 524416

// Builds W1^T (per d) in workspace and zero-inits the logdet output region.
__global__ void setup_kernel(const float* __restrict__ W1,
                             float* __restrict__ W1T,
                             float* __restrict__ out) {
    int d = blockIdx.x;
    const float* src = W1 + d * H_ * H_;
    float* dst = W1T + d * H_ * H_;
    for (int idx = threadIdx.x; idx < H_ * H_; idx += blockDim.x) {
        int r = idx >> 6, c = idx & 63;
        dst[r * H_ + c] = src[c * H_ + r];   // W1T[d][h_in][h_out] = W1[d][h_out][h_in]
    }
    if (d == 0 && threadIdx.x < B_) out[LOG_OFF + threadIdx.x] = 0.0f;
}

__global__ __launch_bounds__(256) void mlp_kernel(
    const float* __restrict__ x,
    const float* __restrict__ W0, const float* __restrict__ b0,
    const float* __restrict__ b1,
    const float* __restrict__ W2, const float* __restrict__ b2,
    const float* __restrict__ Wo, const float* __restrict__ bo,
    const float* __restrict__ W1T,
    float* __restrict__ out)
{
    const int bid = blockIdx.x;
    const int d   = bid >> 8;          // 256 blocks per d
    const int rem = bid & 255;
    const int b   = rem >> 1;
    const int w   = ((rem & 1) << 8) | threadIdx.x;   // 0..511
    const int n   = b * W_ + w;

    const float* __restrict__ W0d  = W0  + d * (H_ * IN_);
    const float* __restrict__ b0d  = b0  + d * H_;
    const float* __restrict__ b1d  = b1  + d * H_;
    const float* __restrict__ W2d  = W2  + d * (H_ * H_);
    const float* __restrict__ b2d  = b2  + d * H_;
    const float* __restrict__ Wod  = Wo  + d * H_;
    const float* __restrict__ W1Td = W1T + d * (H_ * H_);

    // ---- gather window input: 16 contiguous floats (x[b,w,:], x[b,w+1,:]) + x[b,w+2,d]
    float inp[IN_];
    const float* xp = x + (b * T_ + w) * D_;
    {
        const float4* xp4 = (const float4*)xp;  // 32B-aligned: (b*514+w)*8 floats
        float4 q0 = xp4[0], q1 = xp4[1], q2 = xp4[2], q3 = xp4[3];
        inp[0]=q0.x;  inp[1]=q0.y;  inp[2]=q0.z;  inp[3]=q0.w;
        inp[4]=q1.x;  inp[5]=q1.y;  inp[6]=q1.z;  inp[7]=q1.w;
        inp[8]=q2.x;  inp[9]=q2.y;  inp[10]=q2.z; inp[11]=q2.w;
        inp[12]=q3.x; inp[13]=q3.y; inp[14]=q3.z; inp[15]=q3.w;
        inp[16] = xp[16 + d];
    }

    // ---- Phase A: layer0 (dot) fused with layer1 (outer-product via W1^T rows)
    float h1acc[H_];
#pragma unroll
    for (int g = 0; g < H_; ++g) h1acc[g] = b1d[g];

    unsigned long long m0 = 0ull;

#pragma unroll 1
    for (int h = 0; h < H_; ++h) {
        const float* w0r = W0d + h * IN_;
        float t0 = b0d[h], t1 = 0.f, t2 = 0.f, t3 = 0.f;
#pragma unroll
        for (int i = 0; i < 16; i += 4) {
            t0 = fmaf(inp[i+0], w0r[i+0], t0);
            t1 = fmaf(inp[i+1], w0r[i+1], t1);
            t2 = fmaf(inp[i+2], w0r[i+2], t2);
            t3 = fmaf(inp[i+3], w0r[i+3], t3);
        }
        t0 = fmaf(inp[16], w0r[16], t0);
        float hv = (t0 + t2) + (t1 + t3);
        bool  p  = hv > 0.0f;
        float a0h = p ? hv : hv * SLOPE_;
        m0 |= ((unsigned long long)p) << h;
        const float* w1tr = W1Td + h * H_;
#pragma unroll
        for (int g = 0; g < H_; ++g) h1acc[g] = fmaf(a0h, w1tr[g], h1acc[g]);
    }

    // ---- Phase B: leaky in place (h1acc becomes a1; sign preserved so mask m1 recoverable)
#pragma unroll
    for (int g = 0; g < H_; ++g) {
        float hv = h1acc[g];
        h1acc[g] = hv > 0.0f ? hv : hv * SLOPE_;
    }

    // ---- Phase C: layer2 dot + out-dot + backward-through-W2 outer product (same row reuse)
    float g2acc[H_];
#pragma unroll
    for (int k = 0; k < H_; ++k) g2acc[k] = 0.0f;
    float outv = bo[d];

#pragma unroll 1
    for (int g = 0; g < H_; ++g) {
        const float* w2r = W2d + g * H_;
        float t0 = b2d[g], t1 = 0.f, t2 = 0.f, t3 = 0.f;
#pragma unroll
        for (int k = 0; k < H_; k += 4) {
            t0 = fmaf(h1acc[k+0], w2r[k+0], t0);
            t1 = fmaf(h1acc[k+1], w2r[k+1], t1);
            t2 = fmaf(h1acc[k+2], w2r[k+2], t2);
            t3 = fmaf(h1acc[k+3], w2r[k+3], t3);
        }
        float hv = (t0 + t2) + (t1 + t3);
        bool  p  = hv > 0.0f;
        float a2g = p ? hv : hv * SLOPE_;
        float gb  = Wod[g] * (p ? 1.0f : SLOPE_);
        outv = fmaf(Wod[g], a2g, outv);
#pragma unroll
        for (int k = 0; k < H_; ++k) g2acc[k] = fmaf(gb, w2r[k], g2acc[k]);
    }

    out[n * D_ + d] = outv;   // residuals[b,w,d]

    // ---- Phase D: apply m1 (sign of a1 == sign of h1)
#pragma unroll
    for (int k = 0; k < H_; ++k)
        g2acc[k] *= (h1acc[k] > 0.0f ? 1.0f : SLOPE_);

    // ---- Phase E/F: backward through W1 (dot via W1^T row) fused with jac outer product (W0 row)
    float jac[IN_];
#pragma unroll
    for (int i = 0; i < IN_; ++i) jac[i] = 0.0f;

#pragma unroll 1
    for (int j = 0; j < H_; ++j) {
        const float* w1tr = W1Td + j * H_;
        float t0 = 0.f, t1 = 0.f, t2 = 0.f, t3 = 0.f;
#pragma unroll
        for (int k = 0; k < H_; k += 4) {
            t0 = fmaf(g2acc[k+0], w1tr[k+0], t0);
            t1 = fmaf(g2acc[k+1], w1tr[k+1], t1);
            t2 = fmaf(g2acc[k+2], w1tr[k+2], t2);
            t3 = fmaf(g2acc[k+3], w1tr[k+3], t3);
        }
        float g3j = ((t0 + t2) + (t1 + t3)) * (((m0 >> j) & 1ull) ? 1.0f : SLOPE_);
        const float* w0r = W0d + j * IN_;
#pragma unroll
        for (int i = 0; i < IN_; ++i) jac[i] = fmaf(g3j, w0r[i], jac[i]);
    }

    // hist_jac[d][n][0..15]
    float4* hj = (float4*)(out + HJ_OFF + (d * N_ + n) * 16);
    hj[0] = make_float4(jac[0],  jac[1],  jac[2],  jac[3]);
    hj[1] = make_float4(jac[4],  jac[5],  jac[6],  jac[7]);
    hj[2] = make_float4(jac[8],  jac[9],  jac[10], jac[11]);
    hj[3] = make_float4(jac[12], jac[13], jac[14], jac[15]);

    // logdet: wave reduce then one atomic per block into out[LOG_OFF + b]
    float ld = logf(fabsf(jac[16]));
#pragma unroll
    for (int off = 32; off > 0; off >>= 1)
        ld += __shfl_down(ld, off, 64);

    __shared__ float red[4];
    const int lane = threadIdx.x & 63;
    const int wv   = threadIdx.x >> 6;
    if (lane == 0) red[wv] = ld;
    __syncthreads();
    if (threadIdx.x == 0)
        atomicAdd(out + LOG_OFF + b, (red[0] + red[1]) + (red[2] + red[3]));
}

extern "C" void kernel_launch(void* const* d_in, const int* in_sizes, int n_in,
                              void* d_out, int out_size, void* d_ws, size_t ws_size,
                              hipStream_t stream) {
    const float* x  = (const float*)d_in[0];
    const float* W0 = (const float*)d_in[1];
    const float* b0 = (const float*)d_in[2];
    const float* W1 = (const float*)d_in[3];
    const float* b1 = (const float*)d_in[4];
    const float* W2 = (const float*)d_in[5];
    const float* b2 = (const float*)d_in[6];
    const float* Wo = (const float*)d_in[7];
    const float* bo = (const float*)d_in[8];
    float* out = (float*)d_out;
    float* W1T = (float*)d_ws;   // needs 8*64*64*4 = 128 KiB

    hipLaunchKernelGGL(setup_kernel, dim3(D_), dim3(256), 0, stream, W1, W1T, out);
    hipLaunchKernelGGL(mlp_kernel, dim3(D_ * B_ * 2), dim3(256), 0, stream,
                       x, W0, b0, b1, W2, b2, Wo, bo, W1T, out);
}

// Round 2
// 342.113 us; speedup vs baseline: 1.0021x; 1.0021x over previous
//
#include <hip/hip_runtime.h>
#include <math.h>

#define D_ 8
#define H_ 64
#define IN_ 17
#define SLOPE_ 0.2f
#define B_ 128
#define T_ 514
#define W_ 512
#define N_ (B_*W_)            // 65536
#define RES_SZ (N_*D_)        // 524288
#define LOG_OFF RES_SZ        // 524288
#define HJ_OFF (RES_SZ + B_)  // 524416

// Builds W1^T (per d) in workspace and zero-inits the logdet output region.
__global__ void setup_kernel(const float* __restrict__ W1,
                             float* __restrict__ W1T,
                             float* __restrict__ out) {
    int d = blockIdx.x;
    const float* src = W1 + d * H_ * H_;
    float* dst = W1T + d * H_ * H_;
    for (int idx = threadIdx.x; idx < H_ * H_; idx += blockDim.x) {
        int r = idx >> 6, c = idx & 63;
        dst[r * H_ + c] = src[c * H_ + r];   // W1T[d][h_in][h_out] = W1[d][h_out][h_in]
    }
    if (d == 0 && threadIdx.x < B_) out[LOG_OFF + threadIdx.x] = 0.0f;
}

// (256, 2): allow up to ~256 combined regs/thread so the 64-float accumulator
// arrays live in ARCH VGPRs (VALU-addressable), not AGPRs. R1's VGPR_Count=72
// with no scratch traffic proved the compiler parked the arrays in AGPRs,
// taxing every accumulate with v_accvgpr_read/write.
__global__ __launch_bounds__(256, 2) void mlp_kernel(
    const float* __restrict__ x,
    const float* __restrict__ W0, const float* __restrict__ b0,
    const float* __restrict__ b1,
    const float* __restrict__ W2, const float* __restrict__ b2,
    const float* __restrict__ Wo, const float* __restrict__ bo,
    const float* __restrict__ W1T,
    float* __restrict__ out)
{
    const int bid = blockIdx.x;
    const int d   = bid >> 8;          // 256 blocks per d
    const int rem = bid & 255;
    const int b   = rem >> 1;
    const int w   = ((rem & 1) << 8) | threadIdx.x;   // 0..511
    const int n   = b * W_ + w;

    const float* __restrict__ W0d  = W0  + d * (H_ * IN_);
    const float* __restrict__ b0d  = b0  + d * H_;
    const float* __restrict__ b1d  = b1  + d * H_;
    const float* __restrict__ W2d  = W2  + d * (H_ * H_);
    const float* __restrict__ b2d  = b2  + d * H_;
    const float* __restrict__ Wod  = Wo  + d * H_;
    const float* __restrict__ W1Td = W1T + d * (H_ * H_);

    // ---- gather window input: 16 contiguous floats (x[b,w,:], x[b,w+1,:]) + x[b,w+2,d]
    float inp[IN_];
    const float* xp = x + (b * T_ + w) * D_;
    {
        const float4* xp4 = (const float4*)xp;  // 32B-aligned: (b*514+w)*8 floats
        float4 q0 = xp4[0], q1 = xp4[1], q2 = xp4[2], q3 = xp4[3];
        inp[0]=q0.x;  inp[1]=q0.y;  inp[2]=q0.z;  inp[3]=q0.w;
        inp[4]=q1.x;  inp[5]=q1.y;  inp[6]=q1.z;  inp[7]=q1.w;
        inp[8]=q2.x;  inp[9]=q2.y;  inp[10]=q2.z; inp[11]=q2.w;
        inp[12]=q3.x; inp[13]=q3.y; inp[14]=q3.z; inp[15]=q3.w;
        inp[16] = xp[16 + d];
    }

    // ---- Phase A: layer0 (dot) fused with layer1 (outer-product via W1^T rows)
    float h1acc[H_];
#pragma unroll
    for (int g = 0; g < H_; ++g) h1acc[g] = b1d[g];

    unsigned long long m0 = 0ull;

#pragma unroll 1
    for (int h = 0; h < H_; ++h) {
        const float* w0r = W0d + h * IN_;
        float t0 = b0d[h], t1 = 0.f, t2 = 0.f, t3 = 0.f;
#pragma unroll
        for (int i = 0; i < 16; i += 4) {
            t0 = fmaf(inp[i+0], w0r[i+0], t0);
            t1 = fmaf(inp[i+1], w0r[i+1], t1);
            t2 = fmaf(inp[i+2], w0r[i+2], t2);
            t3 = fmaf(inp[i+3], w0r[i+3], t3);
        }
        t0 = fmaf(inp[16], w0r[16], t0);
        float hv = (t0 + t2) + (t1 + t3);
        bool  p  = hv > 0.0f;
        float a0h = p ? hv : hv * SLOPE_;
        m0 |= ((unsigned long long)p) << h;
        const float* w1tr = W1Td + h * H_;
#pragma unroll
        for (int g = 0; g < H_; ++g) h1acc[g] = fmaf(a0h, w1tr[g], h1acc[g]);
    }

    // ---- Phase B: leaky in place (h1acc becomes a1; sign preserved so mask m1 recoverable)
#pragma unroll
    for (int g = 0; g < H_; ++g) {
        float hv = h1acc[g];
        h1acc[g] = hv > 0.0f ? hv : hv * SLOPE_;
    }

    // ---- Phase C: layer2 dot + out-dot + backward-through-W2 outer product (same row reuse)
    float g2acc[H_];
#pragma unroll
    for (int k = 0; k < H_; ++k) g2acc[k] = 0.0f;
    float outv = bo[d];

#pragma unroll 1
    for (int g = 0; g < H_; ++g) {
        const float* w2r = W2d + g * H_;
        float t0 = b2d[g], t1 = 0.f, t2 = 0.f, t3 = 0.f;
#pragma unroll
        for (int k = 0; k < H_; k += 4) {
            t0 = fmaf(h1acc[k+0], w2r[k+0], t0);
            t1 = fmaf(h1acc[k+1], w2r[k+1], t1);
            t2 = fmaf(h1acc[k+2], w2r[k+2], t2);
            t3 = fmaf(h1acc[k+3], w2r[k+3], t3);
        }
        float hv = (t0 + t2) + (t1 + t3);
        bool  p  = hv > 0.0f;
        float a2g = p ? hv : hv * SLOPE_;
        float gb  = Wod[g] * (p ? 1.0f : SLOPE_);
        outv = fmaf(Wod[g], a2g, outv);
#pragma unroll
        for (int k = 0; k < H_; ++k) g2acc[k] = fmaf(gb, w2r[k], g2acc[k]);
    }

    out[n * D_ + d] = outv;   // residuals[b,w,d]

    // ---- Phase D: apply m1 (sign of a1 == sign of h1)
#pragma unroll
    for (int k = 0; k < H_; ++k)
        g2acc[k] *= (h1acc[k] > 0.0f ? 1.0f : SLOPE_);

    // ---- Phase E/F: backward through W1 (dot via W1^T row) fused with jac outer product (W0 row)
    float jac[IN_];
#pragma unroll
    for (int i = 0; i < IN_; ++i) jac[i] = 0.0f;

#pragma unroll 1
    for (int j = 0; j < H_; ++j) {
        const float* w1tr = W1Td + j * H_;
        float t0 = 0.f, t1 = 0.f, t2 = 0.f, t3 = 0.f;
#pragma unroll
        for (int k = 0; k < H_; k += 4) {
            t0 = fmaf(g2acc[k+0], w1tr[k+0], t0);
            t1 = fmaf(g2acc[k+1], w1tr[k+1], t1);
            t2 = fmaf(g2acc[k+2], w1tr[k+2], t2);
            t3 = fmaf(g2acc[k+3], w1tr[k+3], t3);
        }
        float g3j = ((t0 + t2) + (t1 + t3)) * (((m0 >> j) & 1ull) ? 1.0f : SLOPE_);
        const float* w0r = W0d + j * IN_;
#pragma unroll
        for (int i = 0; i < IN_; ++i) jac[i] = fmaf(g3j, w0r[i], jac[i]);
    }

    // hist_jac[d][n][0..15]
    float4* hj = (float4*)(out + HJ_OFF + (d * N_ + n) * 16);
    hj[0] = make_float4(jac[0],  jac[1],  jac[2],  jac[3]);
    hj[1] = make_float4(jac[4],  jac[5],  jac[6],  jac[7]);
    hj[2] = make_float4(jac[8],  jac[9],  jac[10], jac[11]);
    hj[3] = make_float4(jac[12], jac[13], jac[14], jac[15]);

    // logdet: wave reduce then one atomic per block into out[LOG_OFF + b]
    float ld = logf(fabsf(jac[16]));
#pragma unroll
    for (int off = 32; off > 0; off >>= 1)
        ld += __shfl_down(ld, off, 64);

    __shared__ float red[4];
    const int lane = threadIdx.x & 63;
    const int wv   = threadIdx.x >> 6;
    if (lane == 0) red[wv] = ld;
    __syncthreads();
    if (threadIdx.x == 0)
        atomicAdd(out + LOG_OFF + b, (red[0] + red[1]) + (red[2] + red[3]));
}

extern "C" void kernel_launch(void* const* d_in, const int* in_sizes, int n_in,
                              void* d_out, int out_size, void* d_ws, size_t ws_size,
                              hipStream_t stream) {
    const float* x  = (const float*)d_in[0];
    const float* W0 = (const float*)d_in[1];
    const float* b0 = (const float*)d_in[2];
    const float* W1 = (const float*)d_in[3];
    const float* b1 = (const float*)d_in[4];
    const float* W2 = (const float*)d_in[5];
    const float* b2 = (const float*)d_in[6];
    const float* Wo = (const float*)d_in[7];
    const float* bo = (const float*)d_in[8];
    float* out = (float*)d_out;
    float* W1T = (float*)d_ws;   // needs 8*64*64*4 = 128 KiB

    hipLaunchKernelGGL(setup_kernel, dim3(D_), dim3(256), 0, stream, W1, W1T, out);
    hipLaunchKernelGGL(mlp_kernel, dim3(D_ * B_ * 2), dim3(256), 0, stream,
                       x, W0, b0, b1, W2, b2, Wo, bo, W1T, out);
}